// Round 4
// baseline (295.747 us; speedup 1.0000x reference)
//
#include <hip/hip_runtime.h>

#define BDIM 4
#define HDIM 16
#define SDIM 4096
#define DDIM 64
#define NBH (BDIM * HDIM)

#define BH_STRIDE (DDIM * DDIM + DDIM)      // 4160 floats: [kv 64x64][kone 64]
#define CHUNK_FLOATS (NBH * BH_STRIDE)      // 266240 floats = 1,064,960 B

__device__ __forceinline__ float phi_f(float x) {
    // elu(x)+1 = x+1 (x>0) else exp(x)
    return x > 0.0f ? x + 1.0f : __expf(x);
}

// -------- Phase 1: partial kv[d][e] = sum_s phiK[s][d]*V[s][e]; kone[d] = sum_s phiK[s][d]
// 128 thr = 2 independent waves. 8x8 acc/thread covers the full 64x64 per wave.
// No LDS / no barriers in the main loop: the whole wave walks the same s-row, so
// K/V row reads are one contiguous 256-B wave-load with 8-way lane dedup.
template<bool ATOMIC>
__global__ __launch_bounds__(128, 3) void la_phase1(
    const float* __restrict__ K, const float* __restrict__ V,
    const float* __restrict__ mask, float* __restrict__ outp, int chunk_rows)
{
    __shared__ float comb[DDIM * DDIM];     // 16 KB cross-wave combine
    __shared__ float combk1[DDIM];

    const int bh = blockIdx.y;
    const int b  = bh / HDIM;
    const int t  = threadIdx.x;
    const int w  = t >> 6;                  // wave 0/1
    const int l  = t & 63;
    const int d0 = (l >> 3) << 3;           // 0,8,...,56 (8 lanes share each d0)
    const int e0 = (l & 7) << 3;            // 0,8,...,56 (8 lanes share each e0)

    const int rpw = chunk_rows >> 1;        // rows per wave
    const int s0  = blockIdx.x * chunk_rows + w * rpw;

    const float* Kb = K + (size_t)bh * SDIM * DDIM;
    const float* Vb = V + (size_t)bh * SDIM * DDIM;
    const float* mb = mask + (size_t)b * SDIM;
    const float scale = 0.35355339059327373f;   // 64^-0.25

    float acc[8][8] = {};
    float k1[8] = {};

    // prefetch row s0
    float4 ka0 = *(const float4*)(Kb + (size_t)s0 * DDIM + d0);
    float4 ka1 = *(const float4*)(Kb + (size_t)s0 * DDIM + d0 + 4);
    float4 va0 = *(const float4*)(Vb + (size_t)s0 * DDIM + e0);
    float4 va1 = *(const float4*)(Vb + (size_t)s0 * DDIM + e0 + 4);
    float  mc  = mb[s0];

    #pragma unroll 2
    for (int i = 0; i < rpw; ++i) {
        // prefetch next row (clamped re-load on last iter keeps vmem uniform)
        const int sn = s0 + ((i + 1 < rpw) ? (i + 1) : i);
        const float4 kb0 = *(const float4*)(Kb + (size_t)sn * DDIM + d0);
        const float4 kb1 = *(const float4*)(Kb + (size_t)sn * DDIM + d0 + 4);
        const float4 vb0 = *(const float4*)(Vb + (size_t)sn * DDIM + e0);
        const float4 vb1 = *(const float4*)(Vb + (size_t)sn * DDIM + e0 + 4);
        const float  mn  = mb[sn];

        float a[8], v[8];
        a[0] = phi_f(ka0.x * scale) * mc;  a[1] = phi_f(ka0.y * scale) * mc;
        a[2] = phi_f(ka0.z * scale) * mc;  a[3] = phi_f(ka0.w * scale) * mc;
        a[4] = phi_f(ka1.x * scale) * mc;  a[5] = phi_f(ka1.y * scale) * mc;
        a[6] = phi_f(ka1.z * scale) * mc;  a[7] = phi_f(ka1.w * scale) * mc;
        v[0] = va0.x; v[1] = va0.y; v[2] = va0.z; v[3] = va0.w;
        v[4] = va1.x; v[5] = va1.y; v[6] = va1.z; v[7] = va1.w;

        #pragma unroll
        for (int x = 0; x < 8; ++x) k1[x] += a[x];

        #pragma unroll
        for (int x = 0; x < 8; ++x)
            #pragma unroll
            for (int y = 0; y < 8; ++y)
                acc[x][y] += a[x] * v[y];

        ka0 = kb0; ka1 = kb1; va0 = vb0; va1 = vb1; mc = mn;
    }

    // ---- cross-wave combine (once per block)
    __syncthreads();
    if (w == 1) {
        #pragma unroll
        for (int i = 0; i < 8; ++i) {
            *(float4*)&comb[(d0 + i) * DDIM + e0]     = make_float4(acc[i][0], acc[i][1], acc[i][2], acc[i][3]);
            *(float4*)&comb[(d0 + i) * DDIM + e0 + 4] = make_float4(acc[i][4], acc[i][5], acc[i][6], acc[i][7]);
        }
        if (e0 == 0) {
            #pragma unroll
            for (int i = 0; i < 8; ++i) combk1[d0 + i] = k1[i];
        }
    }
    __syncthreads();
    if (w == 0) {
        float* base = ATOMIC ? (outp + (size_t)bh * BH_STRIDE)
                             : (outp + ((size_t)blockIdx.x * NBH + bh) * BH_STRIDE);
        #pragma unroll
        for (int i = 0; i < 8; ++i) {
            float4 o0 = *(const float4*)&comb[(d0 + i) * DDIM + e0];
            float4 o1 = *(const float4*)&comb[(d0 + i) * DDIM + e0 + 4];
            o0.x += acc[i][0]; o0.y += acc[i][1]; o0.z += acc[i][2]; o0.w += acc[i][3];
            o1.x += acc[i][4]; o1.y += acc[i][5]; o1.z += acc[i][6]; o1.w += acc[i][7];
            if (ATOMIC) {
                float* p = base + (d0 + i) * DDIM + e0;
                atomicAdd(p + 0, o0.x); atomicAdd(p + 1, o0.y); atomicAdd(p + 2, o0.z); atomicAdd(p + 3, o0.w);
                atomicAdd(p + 4, o1.x); atomicAdd(p + 5, o1.y); atomicAdd(p + 6, o1.z); atomicAdd(p + 7, o1.w);
            } else {
                *(float4*)(base + (d0 + i) * DDIM + e0)     = o0;
                *(float4*)(base + (d0 + i) * DDIM + e0 + 4) = o1;
            }
        }
        if (e0 == 0) {
            #pragma unroll
            for (int i = 0; i < 8; ++i) {
                const float k1t = k1[i] + combk1[d0 + i];
                if (ATOMIC) atomicAdd(&base[DDIM * DDIM + d0 + i], k1t);
                else        base[DDIM * DDIM + d0 + i] = k1t;
            }
        }
    }
}

// -------- Reduce: fin[i] = sum_c part[c][i]
__global__ __launch_bounds__(256) void la_reduce(
    const float* __restrict__ part, float* __restrict__ fin, int nc)
{
    const int g = blockIdx.x * 256 + threadIdx.x;     // float4 index (66560 total)
    const float4* p4 = (const float4*)part;
    float4 s = p4[g];
    for (int c = 1; c < nc; ++c) {
        const float4 v = p4[(size_t)c * (CHUNK_FLOATS / 4) + g];
        s.x += v.x; s.y += v.y; s.z += v.z; s.w += v.w;
    }
    ((float4*)fin)[g] = s;
}

// -------- Phase 2: out[s][e] = (phiQ[s]·kv[:,e]) / (phiQ[s]·kone + 1e-8)
// 256 thr, 128 rows/block, 4r x 8e acc/thread. Q rows in registers (8-lane
// dedup per load), only kv+kone in LDS, one barrier total.
__global__ __launch_bounds__(256, 4) void la_phase2(
    const float* __restrict__ Q, const float* __restrict__ mask,
    const float* __restrict__ fin_all, float* __restrict__ out)
{
    __shared__ float kvL[DDIM * DDIM];      // 16 KB [d*64+e]
    __shared__ float koL[DDIM];

    const int bh = blockIdx.y;
    const int b  = bh / HDIM;
    const int t  = threadIdx.x;             // 0..255
    const int s_base = blockIdx.x * 128;

    const float scale = 0.35355339059327373f;
    const float* fin = fin_all + (size_t)bh * BH_STRIDE;

    // coop load kv + kone into LDS
    {
        const float4* src = (const float4*)fin;
        float4* dst = (float4*)kvL;
        #pragma unroll
        for (int i = 0; i < 4; ++i) dst[t + 256 * i] = src[t + 256 * i];
        if (t < DDIM) koL[t] = fin[DDIM * DDIM + t];
    }
    __syncthreads();

    const int e0 = (t & 7) << 3;            // 0,8,...,56
    const int r0 = (t >> 3) << 2;           // 0,4,...,124
    const float* Qb = Q + (size_t)bh * SDIM * DDIM;
    const float* mb = mask + (size_t)b * SDIM;
    const size_t rowoff = (size_t)(s_base + r0) * DDIM;

    float mrow[4];
    #pragma unroll
    for (int j = 0; j < 4; ++j) mrow[j] = mb[s_base + r0 + j];

    float acc[4][8] = {};
    float nrm[4] = {};

    // prefetch d-chunk 0
    float4 qa[4];
    #pragma unroll
    for (int j = 0; j < 4; ++j) qa[j] = *(const float4*)(Qb + rowoff + j * DDIM);

    for (int dc = 0; dc < DDIM; dc += 4) {
        const int dn = (dc + 4 < DDIM) ? (dc + 4) : dc;
        float4 qb[4];
        #pragma unroll
        for (int j = 0; j < 4; ++j) qb[j] = *(const float4*)(Qb + rowoff + j * DDIM + dn);

        float a[4][4];
        #pragma unroll
        for (int j = 0; j < 4; ++j) {
            a[j][0] = phi_f(qa[j].x * scale) * mrow[j];
            a[j][1] = phi_f(qa[j].y * scale) * mrow[j];
            a[j][2] = phi_f(qa[j].z * scale) * mrow[j];
            a[j][3] = phi_f(qa[j].w * scale) * mrow[j];
        }

        #pragma unroll
        for (int dd = 0; dd < 4; ++dd) {
            const float ko = koL[dc + dd];
            float bb[8];
            *(float4*)&bb[0] = *(const float4*)&kvL[(dc + dd) * DDIM + e0];
            *(float4*)&bb[4] = *(const float4*)&kvL[(dc + dd) * DDIM + e0 + 4];
            #pragma unroll
            for (int j = 0; j < 4; ++j) {
                nrm[j] += a[j][dd] * ko;
                #pragma unroll
                for (int x = 0; x < 8; ++x) acc[j][x] += a[j][dd] * bb[x];
            }
        }
        #pragma unroll
        for (int j = 0; j < 4; ++j) qa[j] = qb[j];
    }

    float* ob = out + ((size_t)bh * SDIM + s_base + r0) * DDIM;
    #pragma unroll
    for (int j = 0; j < 4; ++j) {
        const float inv = 1.0f / (nrm[j] + 1e-8f);
        *(float4*)(ob + (size_t)j * DDIM + e0) =
            make_float4(acc[j][0] * inv, acc[j][1] * inv, acc[j][2] * inv, acc[j][3] * inv);
        *(float4*)(ob + (size_t)j * DDIM + e0 + 4) =
            make_float4(acc[j][4] * inv, acc[j][5] * inv, acc[j][6] * inv, acc[j][7] * inv);
    }
}

extern "C" void kernel_launch(void* const* d_in, const int* in_sizes, int n_in,
                              void* d_out, int out_size, void* d_ws, size_t ws_size,
                              hipStream_t stream) {
    const float* Q = (const float*)d_in[0];
    const float* K = (const float*)d_in[1];
    const float* V = (const float*)d_in[2];
    const float* M = (const float*)d_in[3];
    float* out = (float*)d_out;

    const size_t chunk_bytes = (size_t)CHUNK_FLOATS * sizeof(float);  // 1,064,960 B

    int nc = 0;
    if      (ws_size >= 33 * chunk_bytes) nc = 32;
    else if (ws_size >= 17 * chunk_bytes) nc = 16;

    if (nc > 0) {
        float* part = (float*)d_ws;
        float* fin  = part + (size_t)nc * CHUNK_FLOATS;
        la_phase1<false><<<dim3(nc, NBH), dim3(128), 0, stream>>>(K, V, M, part, SDIM / nc);
        la_reduce<<<dim3(CHUNK_FLOATS / 4 / 256), dim3(256), 0, stream>>>(part, fin, nc);
        la_phase2<<<dim3(SDIM / 128, NBH), dim3(256), 0, stream>>>(Q, M, fin, out);
    } else {
        float* fin = (float*)d_ws;
        hipMemsetAsync(d_ws, 0, chunk_bytes, stream);
        la_phase1<true><<<dim3(16, NBH), dim3(128), 0, stream>>>(K, V, M, fin, SDIM / 16);
        la_phase2<<<dim3(SDIM / 128, NBH), dim3(256), 0, stream>>>(Q, M, fin, out);
    }
}